// Round 1
// baseline (585.575 us; speedup 1.0000x reference)
//
#include <hip/hip_runtime.h>

// IVP loss: Euler-integrate trajectories through vf_pred and vf_true
// (bilinear sampling, coords clipped to image domain), MSE over all
// (n_steps+1, B, 2, H, W) trajectory coordinates. Step 0 diff == 0.

constexpr int   Bn      = 8;
constexpr int   Hn      = 768;
constexpr int   Wn      = 768;
constexpr int   HWn     = Hn * Wn;
constexpr int   NSTEPS  = 8;
constexpr float DXC     = 0.5f;
// mean over (NSTEPS+1) * B * 2 * H * W elements
constexpr double TOTAL_ELEMS = (double)(NSTEPS + 1) * Bn * 2 * HWn;

__device__ __forceinline__ void bilin(const float* __restrict__ vfx,
                                      const float* __restrict__ vfy,
                                      float x, float y,
                                      float& ox, float& oy) {
    // clip to domain (matches jnp.clip in reference)
    x = fminf(fmaxf(x, 0.0f), (float)(Wn - 1));
    y = fminf(fmaxf(y, 0.0f), (float)(Hn - 1));
    float x0f = floorf(x), y0f = floorf(y);
    float wx = x - x0f, wy = y - y0f;
    int ix0 = (int)x0f, iy0 = (int)y0f;
    int ix1 = min(ix0 + 1, Wn - 1);
    int iy1 = min(iy0 + 1, Hn - 1);
    int r0 = iy0 * Wn, r1 = iy1 * Wn;
    int i00 = r0 + ix0, i01 = r0 + ix1;
    int i10 = r1 + ix0, i11 = r1 + ix1;
    float wx1 = 1.0f - wx, wy1 = 1.0f - wy;
    {
        float t0 = wx1 * vfx[i00] + wx * vfx[i01];
        float t1 = wx1 * vfx[i10] + wx * vfx[i11];
        ox = wy1 * t0 + wy * t1;
    }
    {
        float t0 = wx1 * vfy[i00] + wx * vfy[i01];
        float t1 = wx1 * vfy[i10] + wx * vfy[i11];
        oy = wy1 * t0 + wy * t1;
    }
}

__global__ __launch_bounds__(256)
void ivp_loss_kernel(const float* __restrict__ vp,
                     const float* __restrict__ vt,
                     double* __restrict__ acc) {
    int i = blockIdx.x * blockDim.x + threadIdx.x;
    float local = 0.0f;
    if (i < Bn * HWn) {
        int b  = i / HWn;
        int p  = i - b * HWn;
        int yi = p / Wn;
        int xi = p - yi * Wn;
        const float* vpx = vp + (size_t)b * 2 * HWn;
        const float* vpy = vpx + HWn;
        const float* vtx = vt + (size_t)b * 2 * HWn;
        const float* vty = vtx + HWn;
        float pxp = (float)xi, pyp = (float)yi;   // pred trajectory
        float pxt = pxp,       pyt = pyp;         // true trajectory
#pragma unroll
        for (int s = 0; s < NSTEPS; ++s) {
            float ux, uy;
            bilin(vpx, vpy, pxp, pyp, ux, uy);
            pxp = fmaf(DXC, ux, pxp);
            pyp = fmaf(DXC, uy, pyp);
            bilin(vtx, vty, pxt, pyt, ux, uy);
            pxt = fmaf(DXC, ux, pxt);
            pyt = fmaf(DXC, uy, pyt);
            float ddx = pxt - pxp, ddy = pyt - pyp;
            local = fmaf(ddx, ddx, local);
            local = fmaf(ddy, ddy, local);
        }
    }
    // wave64 butterfly reduce
#pragma unroll
    for (int o = 32; o > 0; o >>= 1) local += __shfl_down(local, o, 64);
    __shared__ float wsum[4];
    int lane = threadIdx.x & 63, wid = threadIdx.x >> 6;
    if (lane == 0) wsum[wid] = local;
    __syncthreads();
    if (threadIdx.x == 0) {
        float bs = (wsum[0] + wsum[1]) + (wsum[2] + wsum[3]);
        atomicAdd(acc, (double)bs);
    }
}

__global__ void finalize_kernel(const double* __restrict__ acc,
                                float* __restrict__ out) {
    out[0] = (float)(acc[0] / TOTAL_ELEMS);
}

extern "C" void kernel_launch(void* const* d_in, const int* in_sizes, int n_in,
                              void* d_out, int out_size, void* d_ws, size_t ws_size,
                              hipStream_t stream) {
    const float* vp = (const float*)d_in[0];  // vf_pred
    const float* vt = (const float*)d_in[1];  // vf_true
    double* acc = (double*)d_ws;
    hipMemsetAsync(acc, 0, sizeof(double), stream);
    int total  = Bn * HWn;
    int blocks = (total + 255) / 256;
    ivp_loss_kernel<<<blocks, 256, 0, stream>>>(vp, vt, acc);
    finalize_kernel<<<1, 1, 0, stream>>>(acc, (float*)d_out);
}

// Round 2
// 490.881 us; speedup vs baseline: 1.1929x; 1.1929x over previous
//
#include <hip/hip_runtime.h>

// IVP loss: Euler-integrate trajectories through vf_pred and vf_true
// (bilinear sampling, coords clipped to image domain), MSE over all
// (n_steps+1, B, 2, H, W) trajectory coordinates. Step 0 diff == 0.
//
// R1: latency-bound fix — 4 independent chains per thread (ILP) +
// batch<->XCD blockIdx mapping for L2 locality.

constexpr int   Bn      = 8;
constexpr int   Hn      = 768;
constexpr int   Wn      = 768;
constexpr int   HWn     = Hn * Wn;
constexpr int   NSTEPS  = 8;
constexpr float DXC     = 0.5f;
constexpr int   PPT     = 4;                 // pixel-chains per thread
constexpr int   TPB     = 256;
constexpr int   PIX_PER_BLOCK    = TPB * PPT;            // 1024
constexpr int   BLOCKS_PER_BATCH = HWn / PIX_PER_BLOCK;  // 576
// mean over (NSTEPS+1) * B * 2 * H * W elements
constexpr double TOTAL_ELEMS = (double)(NSTEPS + 1) * Bn * 2 * HWn;

__device__ __forceinline__ void bilin(const float* __restrict__ vfx,
                                      const float* __restrict__ vfy,
                                      float x, float y,
                                      float& ox, float& oy) {
    // clip to domain (matches jnp.clip in reference)
    x = fminf(fmaxf(x, 0.0f), (float)(Wn - 1));
    y = fminf(fmaxf(y, 0.0f), (float)(Hn - 1));
    float x0f = floorf(x), y0f = floorf(y);
    float wx = x - x0f, wy = y - y0f;
    int ix0 = (int)x0f, iy0 = (int)y0f;
    int ix1 = min(ix0 + 1, Wn - 1);
    int iy1 = min(iy0 + 1, Hn - 1);
    int r0 = iy0 * Wn, r1 = iy1 * Wn;
    int i00 = r0 + ix0, i01 = r0 + ix1;
    int i10 = r1 + ix0, i11 = r1 + ix1;
    float wx1 = 1.0f - wx, wy1 = 1.0f - wy;
    {
        float t0 = wx1 * vfx[i00] + wx * vfx[i01];
        float t1 = wx1 * vfx[i10] + wx * vfx[i11];
        ox = wy1 * t0 + wy * t1;
    }
    {
        float t0 = wx1 * vfy[i00] + wx * vfy[i01];
        float t1 = wx1 * vfy[i10] + wx * vfy[i11];
        oy = wy1 * t0 + wy * t1;
    }
}

__global__ __launch_bounds__(TPB)
void ivp_loss_kernel(const float* __restrict__ vp,
                     const float* __restrict__ vt,
                     double* __restrict__ acc) {
    // batch <-> XCD alignment: round-robin dispatch puts blockIdx%8 on XCD idx%8
    int batch = blockIdx.x & 7;
    int seq   = blockIdx.x >> 3;          // 0 .. BLOCKS_PER_BATCH-1
    const float* vpx = vp + (size_t)batch * 2 * HWn;
    const float* vpy = vpx + HWn;
    const float* vtx = vt + (size_t)batch * 2 * HWn;
    const float* vty = vtx + HWn;

    int base = seq * PIX_PER_BLOCK + (int)threadIdx.x;

    float pxp[PPT], pyp[PPT], pxt[PPT], pyt[PPT];
#pragma unroll
    for (int c = 0; c < PPT; ++c) {
        int p  = base + c * TPB;          // 256 consecutive x per chain-segment
        int yi = p / Wn;
        int xi = p - yi * Wn;
        pxp[c] = (float)xi; pyp[c] = (float)yi;
        pxt[c] = (float)xi; pyt[c] = (float)yi;
    }

    float local = 0.0f;
#pragma unroll
    for (int s = 0; s < NSTEPS; ++s) {
#pragma unroll
        for (int c = 0; c < PPT; ++c) {
            float ux, uy;
            bilin(vpx, vpy, pxp[c], pyp[c], ux, uy);
            pxp[c] = fmaf(DXC, ux, pxp[c]);
            pyp[c] = fmaf(DXC, uy, pyp[c]);
            bilin(vtx, vty, pxt[c], pyt[c], ux, uy);
            pxt[c] = fmaf(DXC, ux, pxt[c]);
            pyt[c] = fmaf(DXC, uy, pyt[c]);
            float ddx = pxt[c] - pxp[c], ddy = pyt[c] - pyp[c];
            local = fmaf(ddx, ddx, local);
            local = fmaf(ddy, ddy, local);
        }
    }

    // wave64 butterfly reduce
#pragma unroll
    for (int o = 32; o > 0; o >>= 1) local += __shfl_down(local, o, 64);
    __shared__ float wsum[TPB / 64];
    int lane = threadIdx.x & 63, wid = threadIdx.x >> 6;
    if (lane == 0) wsum[wid] = local;
    __syncthreads();
    if (threadIdx.x == 0) {
        float bs = (wsum[0] + wsum[1]) + (wsum[2] + wsum[3]);
        atomicAdd(acc, (double)bs);
    }
}

__global__ void finalize_kernel(const double* __restrict__ acc,
                                float* __restrict__ out) {
    out[0] = (float)(acc[0] / TOTAL_ELEMS);
}

extern "C" void kernel_launch(void* const* d_in, const int* in_sizes, int n_in,
                              void* d_out, int out_size, void* d_ws, size_t ws_size,
                              hipStream_t stream) {
    const float* vp = (const float*)d_in[0];  // vf_pred
    const float* vt = (const float*)d_in[1];  // vf_true
    double* acc = (double*)d_ws;
    hipMemsetAsync(acc, 0, sizeof(double), stream);
    int blocks = Bn * BLOCKS_PER_BATCH;       // 4608
    ivp_loss_kernel<<<blocks, TPB, 0, stream>>>(vp, vt, acc);
    finalize_kernel<<<1, 1, 0, stream>>>(acc, (float*)d_out);
}

// Round 3
// 316.665 us; speedup vs baseline: 1.8492x; 1.5502x over previous
//
#include <hip/hip_runtime.h>

// IVP loss: Euler-integrate trajectories through vf_pred and vf_true
// (bilinear sampling, coords clipped to image domain), MSE over all
// (n_steps+1, B, 2, H, W) trajectory coordinates. Step 0 diff == 0.
//
// R2: latency-bound fix round 2.
//  - prepass interleaves planar (2,H,W) -> (H,W) float2 so each bilinear
//    corner is ONE dwordx2 gather instead of two dword gathers.
//  - main kernel: per step, two-phase body (issue ALL loads into live
//    register arrays, then combine) to force in-flight ILP the compiler
//    denied us in R1 (VGPR_Count=20 => serialized loads).
//  - PPT=2 chains/thread, batch<->XCD blockIdx mapping kept from R1.

constexpr int   Bn      = 8;
constexpr int   Hn      = 768;
constexpr int   Wn      = 768;
constexpr int   HWn     = Hn * Wn;
constexpr int   NSTEPS  = 8;
constexpr float DXC     = 0.5f;
constexpr int   TPB     = 256;
constexpr int   PPT     = 2;                              // chains per thread
constexpr int   PIX_PER_BLOCK    = TPB * PPT;             // 512
constexpr int   BLOCKS_PER_BATCH = HWn / PIX_PER_BLOCK;   // 1152
constexpr double TOTAL_ELEMS = (double)(NSTEPS + 1) * Bn * 2 * HWn;

// ---------------- prepass: planar -> interleaved float2 ----------------
__global__ __launch_bounds__(256)
void interleave_kernel(const float* __restrict__ vp,
                       const float* __restrict__ vt,
                       float2* __restrict__ wp,
                       float2* __restrict__ wt) {
    int t    = blockIdx.x * blockDim.x + threadIdx.x;
    int base = t * 4;                      // HWn % 4 == 0: groups never straddle batches
    int b    = base / HWn;
    int p    = base - b * HWn;
    {
        const float* px = vp + (size_t)b * 2 * HWn + p;
        const float* py = px + HWn;
        float4 xs = *(const float4*)px;
        float4 ys = *(const float4*)py;
        float2* o = wp + (size_t)b * HWn + p;
        o[0] = {xs.x, ys.x}; o[1] = {xs.y, ys.y};
        o[2] = {xs.z, ys.z}; o[3] = {xs.w, ys.w};
    }
    {
        const float* px = vt + (size_t)b * 2 * HWn + p;
        const float* py = px + HWn;
        float4 xs = *(const float4*)px;
        float4 ys = *(const float4*)py;
        float2* o = wt + (size_t)b * HWn + p;
        o[0] = {xs.x, ys.x}; o[1] = {xs.y, ys.y};
        o[2] = {xs.z, ys.z}; o[3] = {xs.w, ys.w};
    }
}

// ---------------- bilinear address helper ----------------
__device__ __forceinline__ void addr4(float x, float y,
                                      int& i00, int& i01, int& i10, int& i11,
                                      float& wx, float& wy) {
    x = fminf(fmaxf(x, 0.0f), (float)(Wn - 1));
    y = fminf(fmaxf(y, 0.0f), (float)(Hn - 1));
    float x0f = floorf(x), y0f = floorf(y);
    wx = x - x0f; wy = y - y0f;
    int ix0 = (int)x0f, iy0 = (int)y0f;
    int ix1 = min(ix0 + 1, Wn - 1);
    int iy1 = min(iy0 + 1, Hn - 1);
    i00 = iy0 * Wn + ix0; i01 = iy0 * Wn + ix1;
    i10 = iy1 * Wn + ix0; i11 = iy1 * Wn + ix1;
}

// ---------------- main: interleaved-float2 path ----------------
__global__ __launch_bounds__(TPB)
void ivp_loss_i2(const float2* __restrict__ wp,
                 const float2* __restrict__ wt,
                 double* __restrict__ acc) {
    int batch = blockIdx.x & 7;            // batch <-> XCD alignment
    int seq   = blockIdx.x >> 3;
    const float2* fp = wp + (size_t)batch * HWn;
    const float2* ft = wt + (size_t)batch * HWn;

    int base = seq * PIX_PER_BLOCK + (int)threadIdx.x;

    float pxp[PPT], pyp[PPT], pxt[PPT], pyt[PPT];
#pragma unroll
    for (int c = 0; c < PPT; ++c) {
        int p  = base + c * TPB;
        int yi = p / Wn;
        int xi = p - yi * Wn;
        pxp[c] = (float)xi; pyp[c] = (float)yi;
        pxt[c] = (float)xi; pyt[c] = (float)yi;
    }

    float local = 0.0f;
#pragma unroll
    for (int s = 0; s < NSTEPS; ++s) {
        float2 P[PPT][4], T[PPT][4];
        float  wxp[PPT], wyp[PPT], wxt[PPT], wyt[PPT];
        // phase 1: compute all addresses, issue ALL 16 dwordx2 gathers
#pragma unroll
        for (int c = 0; c < PPT; ++c) {
            int a0, a1, a2, a3;
            addr4(pxp[c], pyp[c], a0, a1, a2, a3, wxp[c], wyp[c]);
            P[c][0] = fp[a0]; P[c][1] = fp[a1];
            P[c][2] = fp[a2]; P[c][3] = fp[a3];
            addr4(pxt[c], pyt[c], a0, a1, a2, a3, wxt[c], wyt[c]);
            T[c][0] = ft[a0]; T[c][1] = ft[a1];
            T[c][2] = ft[a2]; T[c][3] = ft[a3];
        }
        // phase 2: combine (loads above stay in flight across this boundary)
#pragma unroll
        for (int c = 0; c < PPT; ++c) {
            {
                float wx = wxp[c], wy = wyp[c];
                float wx1 = 1.0f - wx, wy1 = 1.0f - wy;
                float ux = wy1 * (wx1 * P[c][0].x + wx * P[c][1].x)
                         + wy  * (wx1 * P[c][2].x + wx * P[c][3].x);
                float uy = wy1 * (wx1 * P[c][0].y + wx * P[c][1].y)
                         + wy  * (wx1 * P[c][2].y + wx * P[c][3].y);
                pxp[c] = fmaf(DXC, ux, pxp[c]);
                pyp[c] = fmaf(DXC, uy, pyp[c]);
            }
            {
                float wx = wxt[c], wy = wyt[c];
                float wx1 = 1.0f - wx, wy1 = 1.0f - wy;
                float ux = wy1 * (wx1 * T[c][0].x + wx * T[c][1].x)
                         + wy  * (wx1 * T[c][2].x + wx * T[c][3].x);
                float uy = wy1 * (wx1 * T[c][0].y + wx * T[c][1].y)
                         + wy  * (wx1 * T[c][2].y + wx * T[c][3].y);
                pxt[c] = fmaf(DXC, ux, pxt[c]);
                pyt[c] = fmaf(DXC, uy, pyt[c]);
            }
            float ddx = pxt[c] - pxp[c], ddy = pyt[c] - pyp[c];
            local = fmaf(ddx, ddx, local);
            local = fmaf(ddy, ddy, local);
        }
    }

    // wave64 butterfly reduce
#pragma unroll
    for (int o = 32; o > 0; o >>= 1) local += __shfl_down(local, o, 64);
    __shared__ float wsum[TPB / 64];
    int lane = threadIdx.x & 63, wid = threadIdx.x >> 6;
    if (lane == 0) wsum[wid] = local;
    __syncthreads();
    if (threadIdx.x == 0) {
        float bs = (wsum[0] + wsum[1]) + (wsum[2] + wsum[3]);
        atomicAdd(acc, (double)bs);
    }
}

// ---------------- fallback: planar path (R1 kernel) ----------------
__device__ __forceinline__ void bilin(const float* __restrict__ vfx,
                                      const float* __restrict__ vfy,
                                      float x, float y,
                                      float& ox, float& oy) {
    float wx, wy; int i00, i01, i10, i11;
    addr4(x, y, i00, i01, i10, i11, wx, wy);
    float wx1 = 1.0f - wx, wy1 = 1.0f - wy;
    ox = wy1 * (wx1 * vfx[i00] + wx * vfx[i01]) + wy * (wx1 * vfx[i10] + wx * vfx[i11]);
    oy = wy1 * (wx1 * vfy[i00] + wx * vfy[i01]) + wy * (wx1 * vfy[i10] + wx * vfy[i11]);
}

__global__ __launch_bounds__(TPB)
void ivp_loss_planar(const float* __restrict__ vp,
                     const float* __restrict__ vt,
                     double* __restrict__ acc) {
    int batch = blockIdx.x & 7;
    int seq   = blockIdx.x >> 3;
    const float* vpx = vp + (size_t)batch * 2 * HWn;
    const float* vpy = vpx + HWn;
    const float* vtx = vt + (size_t)batch * 2 * HWn;
    const float* vty = vtx + HWn;
    int base = seq * PIX_PER_BLOCK + (int)threadIdx.x;
    float pxp[PPT], pyp[PPT], pxt[PPT], pyt[PPT];
#pragma unroll
    for (int c = 0; c < PPT; ++c) {
        int p  = base + c * TPB;
        int yi = p / Wn;
        int xi = p - yi * Wn;
        pxp[c] = (float)xi; pyp[c] = (float)yi;
        pxt[c] = (float)xi; pyt[c] = (float)yi;
    }
    float local = 0.0f;
#pragma unroll
    for (int s = 0; s < NSTEPS; ++s) {
#pragma unroll
        for (int c = 0; c < PPT; ++c) {
            float ux, uy;
            bilin(vpx, vpy, pxp[c], pyp[c], ux, uy);
            pxp[c] = fmaf(DXC, ux, pxp[c]);
            pyp[c] = fmaf(DXC, uy, pyp[c]);
            bilin(vtx, vty, pxt[c], pyt[c], ux, uy);
            pxt[c] = fmaf(DXC, ux, pxt[c]);
            pyt[c] = fmaf(DXC, uy, pyt[c]);
            float ddx = pxt[c] - pxp[c], ddy = pyt[c] - pyp[c];
            local = fmaf(ddx, ddx, local);
            local = fmaf(ddy, ddy, local);
        }
    }
#pragma unroll
    for (int o = 32; o > 0; o >>= 1) local += __shfl_down(local, o, 64);
    __shared__ float wsum[TPB / 64];
    int lane = threadIdx.x & 63, wid = threadIdx.x >> 6;
    if (lane == 0) wsum[wid] = local;
    __syncthreads();
    if (threadIdx.x == 0) {
        float bs = (wsum[0] + wsum[1]) + (wsum[2] + wsum[3]);
        atomicAdd(acc, (double)bs);
    }
}

__global__ void finalize_kernel(const double* __restrict__ acc,
                                float* __restrict__ out) {
    out[0] = (float)(acc[0] / TOTAL_ELEMS);
}

extern "C" void kernel_launch(void* const* d_in, const int* in_sizes, int n_in,
                              void* d_out, int out_size, void* d_ws, size_t ws_size,
                              hipStream_t stream) {
    const float* vp = (const float*)d_in[0];  // vf_pred
    const float* vt = (const float*)d_in[1];  // vf_true
    double* acc = (double*)d_ws;
    hipMemsetAsync(acc, 0, sizeof(double), stream);

    const size_t field_bytes = (size_t)Bn * HWn * sizeof(float2);   // 37.75 MB
    const size_t need = 256 + 2 * field_bytes;
    int blocks = Bn * BLOCKS_PER_BATCH;

    if (ws_size >= need) {
        float2* wpi = (float2*)((char*)d_ws + 256);
        float2* wti = (float2*)((char*)d_ws + 256 + field_bytes);
        int ithreads = Bn * HWn / 4;
        interleave_kernel<<<ithreads / 256, 256, 0, stream>>>(vp, vt, wpi, wti);
        ivp_loss_i2<<<blocks, TPB, 0, stream>>>(wpi, wti, acc);
    } else {
        ivp_loss_planar<<<blocks, TPB, 0, stream>>>(vp, vt, acc);
    }
    finalize_kernel<<<1, 1, 0, stream>>>(acc, (float*)d_out);
}